// Round 2
// baseline (87.166 us; speedup 1.0000x reference)
//
#include <hip/hip_runtime.h>
#include <hip/hip_bf16.h>

typedef float f32x4 __attribute__((ext_vector_type(4)));

// ---------------------------------------------------------------------------
// async global->LDS, 16B per lane. LDS dest must be the wave-uniform base;
// HW adds lane*16. Global src is per-lane.
// ---------------------------------------------------------------------------
__device__ __forceinline__ void gld16(const void* g, void* l) {
    __builtin_amdgcn_global_load_lds(
        (const __attribute__((address_space(1))) void*)g,
        (__attribute__((address_space(3))) void*)l,
        16, 0, 0);
}

// gelu, tanh approximation (matches jax.nn.gelu approximate=True)
__device__ __forceinline__ float gelu_tanh(float x) {
    float u = 0.7978845608028654f * x * (1.0f + 0.044715f * x * x);
    float e = __expf(2.0f * u);
    float t = 1.0f - 2.0f / (e + 1.0f);   // tanh(u)
    return 0.5f * x * (1.0f + t);
}

// ---------------------------------------------------------------------------
// Kernel 1: quantize x (f32 [M][K]) -> fp8 e4m3 [M][K], 4 elems/thread
// ---------------------------------------------------------------------------
__global__ __launch_bounds__(256) void quantA_kernel(
        const float* __restrict__ in, unsigned int* __restrict__ out, int n4) {
    int i = blockIdx.x * 256 + threadIdx.x;
    if (i >= n4) return;
    float4 v = reinterpret_cast<const float4*>(in)[i];
    int pk = 0;
    pk = __builtin_amdgcn_cvt_pk_fp8_f32(v.x, v.y, pk, false); // bytes 0,1
    pk = __builtin_amdgcn_cvt_pk_fp8_f32(v.z, v.w, pk, true);  // bytes 2,3
    out[i] = (unsigned int)pk;
}

// ---------------------------------------------------------------------------
// Kernel 2: quantize + transpose kernel (f32 [K][N]) -> fp8 [N][K]
// 64x64 tiles through LDS.
// ---------------------------------------------------------------------------
__global__ __launch_bounds__(256) void quantBT_kernel(
        const float* __restrict__ B, unsigned char* __restrict__ BT,
        int K, int N) {
    __shared__ unsigned char lds[64 * 68];    // [k=64][n=64], row stride 68 (pad)
    const int tid = threadIdx.x;
    const int n0 = blockIdx.x * 64;
    const int k0 = blockIdx.y * 64;

    #pragma unroll
    for (int p = 0; p < 4; ++p) {
        int s = p * 256 + tid;
        int r = s >> 4;          // k within tile (0..63)
        int c = s & 15;          // float4 group (covers n = 4c..4c+3)
        float4 v = *reinterpret_cast<const float4*>(
            B + (long)(k0 + r) * N + n0 + c * 4);
        int pk = 0;
        pk = __builtin_amdgcn_cvt_pk_fp8_f32(v.x, v.y, pk, false);
        pk = __builtin_amdgcn_cvt_pk_fp8_f32(v.z, v.w, pk, true);
        *reinterpret_cast<unsigned int*>(&lds[r * 68 + c * 4]) = (unsigned int)pk;
    }
    __syncthreads();
    #pragma unroll
    for (int p = 0; p < 4; ++p) {
        int s = p * 256 + tid;
        int n = s >> 4;          // n within tile (0..63)
        int kg = s & 15;         // k group of 4
        unsigned int w = 0;
        #pragma unroll
        for (int j = 0; j < 4; ++j)
            w |= (unsigned int)lds[(kg * 4 + j) * 68 + n] << (8 * j);
        *reinterpret_cast<unsigned int*>(BT + (long)(n0 + n) * K + k0 + kg * 4) = w;
    }
}

// ---------------------------------------------------------------------------
// Kernel 3: fp8 GEMM, C = A[M,K] * BT[N,K]^T, + bias, gelu, -> f32
// 128x128 tile, BK=64, 4 waves (2x2), each wave 64x64 out (4x4 16x16 frags).
// m97-style 2-barrier K-loop with global_load_lds width 16.
// ---------------------------------------------------------------------------
__global__ __launch_bounds__(256) void gemm_fp8_kernel(
        const unsigned char* __restrict__ A,   // [M][K] fp8
        const unsigned char* __restrict__ BT,  // [N][K] fp8
        const float* __restrict__ bias,        // [N]
        float* __restrict__ out,               // [M][N] f32
        int M, int N, int K) {
    constexpr int BM = 128, BN = 128, BK = 64;
    __shared__ unsigned char sA[BM * BK];   // [128][64] linear, row stride 64
    __shared__ unsigned char sB[BN * BK];

    const int tid  = threadIdx.x;
    const int lane = tid & 63;
    const int wid  = tid >> 6;            // 0..3
    const int wm   = wid >> 1, wn = wid & 1;
    const int nTn  = N / BN;
    const int tile_m = blockIdx.x / nTn, tile_n = blockIdx.x % nTn;
    const int m0 = tile_m * BM, n0 = tile_n * BN;

    const int lrow = lane & 15;           // fragment row/col within 16
    const int kgrp = lane >> 4;           // 0..3, k-group of 8

    // staging slots: 512 x 16B per tile, 2 wave-loads per wave per operand
    const int s0 = (wid * 2 + 0) * 64 + lane;
    const int s1 = (wid * 2 + 1) * 64 + lane;
    const int r0 = s0 >> 2, c0 = (s0 & 3) << 4;
    const int r1 = s1 >> 2, c1 = (s1 & 3) << 4;

    f32x4 acc[4][4] = {};

    for (int kt = 0; kt < K; kt += BK) {
        gld16(A  + (long)(m0 + r0) * K + kt + c0, sA + (wid * 2 + 0) * 1024);
        gld16(A  + (long)(m0 + r1) * K + kt + c1, sA + (wid * 2 + 1) * 1024);
        gld16(BT + (long)(n0 + r0) * K + kt + c0, sB + (wid * 2 + 0) * 1024);
        gld16(BT + (long)(n0 + r1) * K + kt + c1, sB + (wid * 2 + 1) * 1024);
        __syncthreads();

        #pragma unroll
        for (int ks = 0; ks < 2; ++ks) {
            long a[4], b[4];
            #pragma unroll
            for (int f = 0; f < 4; ++f) {
                a[f] = *reinterpret_cast<const long*>(
                    &sA[(wm * 64 + f * 16 + lrow) * 64 + ks * 32 + kgrp * 8]);
                b[f] = *reinterpret_cast<const long*>(
                    &sB[(wn * 64 + f * 16 + lrow) * 64 + ks * 32 + kgrp * 8]);
            }
            #pragma unroll
            for (int fi = 0; fi < 4; ++fi)
                #pragma unroll
                for (int fj = 0; fj < 4; ++fj)
                    acc[fi][fj] = __builtin_amdgcn_mfma_f32_16x16x32_fp8_fp8(
                        a[fi], b[fj], acc[fi][fj], 0, 0, 0);
        }
        __syncthreads();
    }

    // epilogue: bias + gelu -> f32
    // C/D layout (16x16, dtype-independent): col = lane&15, row = (lane>>4)*4 + reg
    #pragma unroll
    for (int fj = 0; fj < 4; ++fj) {
        const int col = n0 + wn * 64 + fj * 16 + lrow;
        const float bv = bias[col];
        #pragma unroll
        for (int fi = 0; fi < 4; ++fi) {
            const int rbase = m0 + wm * 64 + fi * 16 + kgrp * 4;
            f32x4 v = acc[fi][fj];
            #pragma unroll
            for (int r = 0; r < 4; ++r) {
                float xv = v[r] + bv;
                out[(long)(rbase + r) * N + col] = gelu_tanh(xv);
            }
        }
    }
}

// ---------------------------------------------------------------------------
extern "C" void kernel_launch(void* const* d_in, const int* in_sizes, int n_in,
                              void* d_out, int out_size, void* d_ws, size_t ws_size,
                              hipStream_t stream) {
    const float* x    = (const float*)d_in[0];   // [tokens][d_in]
    const float* w    = (const float*)d_in[1];   // [d_in][units]
    const float* bias = (const float*)d_in[2];   // [units]
    float* out = (float*)d_out;

    const int units  = in_sizes[2];              // 4096
    const int dmodel = in_sizes[1] / units;      // 1024
    const int tokens = in_sizes[0] / dmodel;     // 4096

    unsigned char* Aq  = (unsigned char*)d_ws;                       // [tokens][dmodel] fp8
    unsigned char* BTq = Aq + (size_t)tokens * dmodel;               // [units][dmodel] fp8

    const int n4a = tokens * dmodel / 4;
    quantA_kernel<<<dim3(n4a / 256), dim3(256), 0, stream>>>(
        x, (unsigned int*)Aq, n4a);

    quantBT_kernel<<<dim3(units / 64, dmodel / 64), dim3(256), 0, stream>>>(
        w, BTq, dmodel, units);

    const int nblocks = (tokens / 128) * (units / 128);
    gemm_fp8_kernel<<<dim3(nblocks), dim3(256), 0, stream>>>(
        Aq, BTq, bias, out, tokens, units, dmodel);
}

// Round 3
// 56.056 us; speedup vs baseline: 1.5550x; 1.5550x over previous
//
#include <hip/hip_runtime.h>
#include <hip/hip_bf16.h>

typedef float f32x4 __attribute__((ext_vector_type(4)));
typedef long  l2    __attribute__((ext_vector_type(2)));

// ---------------------------------------------------------------------------
// async global->LDS, 16B per lane. LDS dest is wave-uniform base (+lane*16).
// ---------------------------------------------------------------------------
__device__ __forceinline__ void gld16(const void* g, void* l) {
    __builtin_amdgcn_global_load_lds(
        (const __attribute__((address_space(1))) void*)g,
        (__attribute__((address_space(3))) void*)l,
        16, 0, 0);
}

// gelu, tanh approximation (matches jax.nn.gelu approximate=True)
__device__ __forceinline__ float gelu_tanh(float x) {
    float u = 0.7978845608028654f * x * (1.0f + 0.044715f * x * x);
    float e = __expf(2.0f * u);
    float t = 1.0f - 2.0f / (e + 1.0f);   // tanh(u)
    return 0.5f * x * (1.0f + t);
}

// ---------------------------------------------------------------------------
// Pre-permuted fp8 storage layout (both A[M][K] and BT[N][K]):
// within each row's 64B k-segment:
//   step 1 (pair ks-halves): chunk g (16B) = orig k-bytes [g*8,+8) ++ [32+g*8,+8)
//   step 2 (bank swizzle):   stored at chunk position c = g ^ ((row>>1)&3)
// GEMM then reads one ds_read_b128 per fragment-pair: lo 8B = ks0, hi = ks1,
// with 8 consecutive lanes spread across all 32 banks.
// orig k-offset o (4-aligned) maps to: g=(o&31)>>3, s=(o&7)+((o>>5)&1)*8
// ---------------------------------------------------------------------------

// Kernel 1: quantize x (f32 [M][K]) -> fp8 e4m3, permuted layout
__global__ __launch_bounds__(256) void quantA_kernel(
        const float* __restrict__ in, unsigned char* __restrict__ out,
        int n4, int K) {
    int i = blockIdx.x * 256 + threadIdx.x;
    if (i >= n4) return;
    float4 v = reinterpret_cast<const float4*>(in)[i];
    int pk = 0;
    pk = __builtin_amdgcn_cvt_pk_fp8_f32(v.x, v.y, pk, false);
    pk = __builtin_amdgcn_cvt_pk_fp8_f32(v.z, v.w, pk, true);
    const long k4 = (long)i * 4;
    const int  row = (int)(k4 / K);
    const int  k   = (int)(k4 % K);
    const int  o   = k & 63;
    const int  g   = (o & 31) >> 3;
    const int  s   = (o & 7) + ((o >> 5) & 1) * 8;
    const int  c   = g ^ ((row >> 1) & 3);
    *reinterpret_cast<unsigned int*>(
        out + (long)row * K + (k & ~63) + (c << 4) + s) = (unsigned int)pk;
}

// Kernel 2: quantize + transpose kernel (f32 [K][N]) -> fp8 BT[N][K], permuted
__global__ __launch_bounds__(256) void quantBT_kernel(
        const float* __restrict__ B, unsigned char* __restrict__ BT,
        int K, int N) {
    __shared__ unsigned char lds[64 * 68];    // [k=64][n=64], row stride 68 (pad)
    const int tid = threadIdx.x;
    const int n0 = blockIdx.x * 64;
    const int k0 = blockIdx.y * 64;

    #pragma unroll
    for (int p = 0; p < 4; ++p) {
        int s = p * 256 + tid;
        int r = s >> 4;          // k within tile (0..63)
        int c = s & 15;          // float4 group (covers n = 4c..4c+3)
        float4 v = *reinterpret_cast<const float4*>(
            B + (long)(k0 + r) * N + n0 + c * 4);
        int pk = 0;
        pk = __builtin_amdgcn_cvt_pk_fp8_f32(v.x, v.y, pk, false);
        pk = __builtin_amdgcn_cvt_pk_fp8_f32(v.z, v.w, pk, true);
        *reinterpret_cast<unsigned int*>(&lds[r * 68 + c * 4]) = (unsigned int)pk;
    }
    __syncthreads();
    #pragma unroll
    for (int p = 0; p < 4; ++p) {
        int sidx = p * 256 + tid;
        int n  = sidx >> 4;      // n within tile (0..63)
        int kg = sidx & 15;      // k group of 4 (orig offset kg*4)
        unsigned int w = 0;
        #pragma unroll
        for (int j = 0; j < 4; ++j)
            w |= (unsigned int)lds[(kg * 4 + j) * 68 + n] << (8 * j);
        const int nn = n0 + n;
        const int o  = kg * 4;                       // orig offset in 64B segment
        const int g  = (o & 31) >> 3;
        const int s  = (o & 7) + ((o >> 5) & 1) * 8;
        const int c  = g ^ ((nn >> 1) & 3);
        *reinterpret_cast<unsigned int*>(
            BT + (long)nn * K + k0 + (c << 4) + s) = w;
    }
}

// ---------------------------------------------------------------------------
// Kernel 3: fp8 GEMM, C = A[M,K] * BT[N,K]^T, + bias, gelu, -> f32
// 128x128 tile, BK=64, 4 waves (2x2). 2-phase double-buffered pipeline:
//   STAGE(next) issued before ds_read+MFMA(cur); one __syncthreads per iter
//   (drains vmcnt for the stage and orders buffer reuse).
// ---------------------------------------------------------------------------
__global__ __launch_bounds__(256) void gemm_fp8_kernel(
        const unsigned char* __restrict__ A,   // [M][K] fp8 (permuted layout)
        const unsigned char* __restrict__ BT,  // [N][K] fp8 (permuted layout)
        const float* __restrict__ bias,        // [N]
        float* __restrict__ out,               // [M][N] f32
        int M, int N, int K) {
    constexpr int BM = 128, BN = 128, BK = 64;
    __shared__ unsigned char sA[2][BM * BK];   // 8KB each
    __shared__ unsigned char sB[2][BN * BK];

    const int tid  = threadIdx.x;
    const int lane = tid & 63;
    const int wid  = tid >> 6;            // 0..3
    const int wm   = wid >> 1, wn = wid & 1;
    const int nTn  = N / BN;
    const int tile_m = blockIdx.x / nTn, tile_n = blockIdx.x % nTn;
    const int m0 = tile_m * BM, n0 = tile_n * BN;

    const int lrow = lane & 15;           // fragment row within 16
    const int kgrp = lane >> 4;           // 0..3, k-group
    const int swz  = (lrow >> 1) & 3;

    // staging slots: two 16B-lane loads per wave per operand
    const int s0 = (wid * 2 + 0) * 64 + lane;
    const int s1 = (wid * 2 + 1) * 64 + lane;
    const int r0 = s0 >> 2, c0 = (s0 & 3) << 4;
    const int r1 = s1 >> 2, c1 = (s1 & 3) << 4;

    const unsigned char* gA0 = A  + (long)(m0 + r0) * K + c0;
    const unsigned char* gA1 = A  + (long)(m0 + r1) * K + c1;
    const unsigned char* gB0 = BT + (long)(n0 + r0) * K + c0;
    const unsigned char* gB1 = BT + (long)(n0 + r1) * K + c1;
    const int l0 = (wid * 2 + 0) * 1024;
    const int l1 = (wid * 2 + 1) * 1024;

    // fragment read base (chunk-swizzled b128: lo=ks0, hi=ks1)
    const int aBase = (wm * 64 + lrow) * 64 + ((kgrp ^ swz) << 4);
    const int bBase = (wn * 64 + lrow) * 64 + ((kgrp ^ swz) << 4);

    f32x4 acc[4][4] = {};

    const int NT = K / BK;
    // prologue: stage tile 0 into buf 0
    gld16(gA0, &sA[0][l0]);
    gld16(gA1, &sA[0][l1]);
    gld16(gB0, &sB[0][l0]);
    gld16(gB1, &sB[0][l1]);
    __syncthreads();

    for (int t = 0; t < NT; ++t) {
        const int cur = t & 1;
        if (t + 1 < NT) {                 // issue next-tile stage first
            const int nxt = cur ^ 1;
            const long ko = (long)(t + 1) * BK;
            gld16(gA0 + ko, &sA[nxt][l0]);
            gld16(gA1 + ko, &sA[nxt][l1]);
            gld16(gB0 + ko, &sB[nxt][l0]);
            gld16(gB1 + ko, &sB[nxt][l1]);
        }

        l2 a[4], b[4];
        #pragma unroll
        for (int f = 0; f < 4; ++f) {
            a[f] = *reinterpret_cast<const l2*>(&sA[cur][aBase + f * 1024]);
            b[f] = *reinterpret_cast<const l2*>(&sB[cur][bBase + f * 1024]);
        }
        #pragma unroll
        for (int ks = 0; ks < 2; ++ks)
            #pragma unroll
            for (int fi = 0; fi < 4; ++fi)
                #pragma unroll
                for (int fj = 0; fj < 4; ++fj)
                    acc[fi][fj] = __builtin_amdgcn_mfma_f32_16x16x32_fp8_fp8(
                        a[fi][ks], b[fj][ks], acc[fi][fj], 0, 0, 0);

        __syncthreads();                  // drains vmcnt(0)+lgkmcnt(0) + barrier
    }

    // epilogue: bias + gelu -> f32
    // C/D layout (16x16, dtype-independent): col = lane&15, row = (lane>>4)*4 + reg
    #pragma unroll
    for (int fj = 0; fj < 4; ++fj) {
        const int col = n0 + wn * 64 + fj * 16 + lrow;
        const float bv = bias[col];
        #pragma unroll
        for (int fi = 0; fi < 4; ++fi) {
            const int rbase = m0 + wm * 64 + fi * 16 + kgrp * 4;
            f32x4 v = acc[fi][fj];
            #pragma unroll
            for (int r = 0; r < 4; ++r) {
                float xv = v[r] + bv;
                out[(long)(rbase + r) * N + col] = gelu_tanh(xv);
            }
        }
    }
}

// ---------------------------------------------------------------------------
extern "C" void kernel_launch(void* const* d_in, const int* in_sizes, int n_in,
                              void* d_out, int out_size, void* d_ws, size_t ws_size,
                              hipStream_t stream) {
    const float* x    = (const float*)d_in[0];   // [tokens][d_in]
    const float* w    = (const float*)d_in[1];   // [d_in][units]
    const float* bias = (const float*)d_in[2];   // [units]
    float* out = (float*)d_out;

    const int units  = in_sizes[2];              // 4096
    const int dmodel = in_sizes[1] / units;      // 1024
    const int tokens = in_sizes[0] / dmodel;     // 4096

    unsigned char* Aq  = (unsigned char*)d_ws;                       // [tokens][dmodel] fp8
    unsigned char* BTq = Aq + (size_t)tokens * dmodel;               // [units][dmodel] fp8

    const int n4a = tokens * dmodel / 4;
    quantA_kernel<<<dim3(n4a / 256), dim3(256), 0, stream>>>(
        x, Aq, n4a, dmodel);

    quantBT_kernel<<<dim3(units / 64, dmodel / 64), dim3(256), 0, stream>>>(
        w, BTq, dmodel, units);

    const int nblocks = (tokens / 128) * (units / 128);
    gemm_fp8_kernel<<<dim3(nblocks), dim3(256), 0, stream>>>(
        Aq, BTq, bias, out, tokens, units, dmodel);
}